// Round 1
// baseline (293.031 us; speedup 1.0000x reference)
//
#include <hip/hip_runtime.h>
#include <hip/hip_bf16.h>
#include <stdint.h>

#define BATCH 4
#define SEQ   2048
#define HEADS 16
#define DHEAD 64
#define DIM   1024
#define NQKV  3072
#define ROWS  (BATCH*SEQ)   // 8192
#define SCALE 0.125f

typedef __attribute__((ext_vector_type(8))) short short8;
typedef __attribute__((ext_vector_type(4))) float f32x4;

__device__ __forceinline__ ushort f2bf(float f) {
    union { float f; uint32_t u; } x; x.f = f;
    uint32_t r = x.u + 0x7fffu + ((x.u >> 16) & 1u);
    return (ushort)(r >> 16);
}

// ---------------- cast x (fp32 -> bf16), 8 elems/thread ----------------
__global__ __launch_bounds__(256) void cvt_x_kernel(
    const float* __restrict__ in, ushort* __restrict__ out, int n8) {
    int i = blockIdx.x * 256 + threadIdx.x;
    if (i >= n8) return;
    f32x4 a = ((const f32x4*)in)[2*i];
    f32x4 b = ((const f32x4*)in)[2*i+1];
    short8 o;
    o[0]=(short)f2bf(a[0]); o[1]=(short)f2bf(a[1]); o[2]=(short)f2bf(a[2]); o[3]=(short)f2bf(a[3]);
    o[4]=(short)f2bf(b[0]); o[5]=(short)f2bf(b[1]); o[6]=(short)f2bf(b[2]); o[7]=(short)f2bf(b[3]);
    ((short8*)out)[i] = o;
}

// ---------------- transpose weights: in[R][C] f32 -> out[C][R] bf16 ----------------
__global__ __launch_bounds__(256) void transpose_w_kernel(
    const float* __restrict__ in, ushort* __restrict__ out, int R, int C) {
    __shared__ float tile[32][33];
    int ctiles = C >> 5;
    int bx = blockIdx.x % ctiles, by = blockIdx.x / ctiles;
    int c0 = bx << 5, r0 = by << 5;
    int tx = threadIdx.x & 31, ty = threadIdx.x >> 5;   // ty: 0..7
#pragma unroll
    for (int it = 0; it < 4; ++it)
        tile[ty + 8*it][tx] = in[(size_t)(r0 + ty + 8*it)*C + c0 + tx];
    __syncthreads();
#pragma unroll
    for (int it = 0; it < 4; ++it)
        out[(size_t)(c0 + ty + 8*it)*R + r0 + tx] = f2bf(tile[tx][ty + 8*it]);
}

// ---------------- GEMM1: xb[8192][1024] @ wqkvT[3072][1024]^T -> Q/K/V bf16 ----------------
__global__ __launch_bounds__(256) void gemm1_kernel(
    const ushort* __restrict__ A, const ushort* __restrict__ BT,
    ushort* __restrict__ Qo, ushort* __restrict__ Ko, ushort* __restrict__ Vo) {
    const int K = DIM;
    __shared__ ushort As[128][32];
    __shared__ ushort Bs[128][32];
    int t = threadIdx.x;
    int lane = t & 63, wid = t >> 6;
    int lo = lane & 15, hi = lane >> 4;
    int wm = wid >> 1, wn = wid & 1;
    int bx = blockIdx.x % (NQKV/128), by = blockIdx.x / (NQKV/128);
    int m0 = by * 128, n0 = bx * 128;
    int sr = t >> 2, sc = (t & 3) * 8;

    const ushort* ga = A  + (size_t)m0 * K + sc;
    const ushort* gb = BT + (size_t)n0 * K + sc;

    f32x4 acc[4][4];
#pragma unroll
    for (int i = 0; i < 4; ++i)
#pragma unroll
        for (int j = 0; j < 4; ++j) acc[i][j] = (f32x4){0.f,0.f,0.f,0.f};

    for (int k0 = 0; k0 < K; k0 += 32) {
        short8 a0 = *(const short8*)(ga + (size_t)sr*K + k0);
        short8 a1 = *(const short8*)(ga + (size_t)(sr+64)*K + k0);
        short8 b0 = *(const short8*)(gb + (size_t)sr*K + k0);
        short8 b1 = *(const short8*)(gb + (size_t)(sr+64)*K + k0);
        __syncthreads();
        *(short8*)&As[sr][sc]    = a0;
        *(short8*)&As[sr+64][sc] = a1;
        *(short8*)&Bs[sr][sc]    = b0;
        *(short8*)&Bs[sr+64][sc] = b1;
        __syncthreads();
        short8 af[4], bf[4];
#pragma unroll
        for (int i = 0; i < 4; ++i) af[i] = *(const short8*)&As[wm*64 + i*16 + lo][hi*8];
#pragma unroll
        for (int j = 0; j < 4; ++j) bf[j] = *(const short8*)&Bs[wn*64 + j*16 + lo][hi*8];
#pragma unroll
        for (int i = 0; i < 4; ++i)
#pragma unroll
            for (int j = 0; j < 4; ++j)
                acc[i][j] = __builtin_amdgcn_mfma_f32_16x16x32_bf16(af[i], bf[j], acc[i][j], 0, 0, 0);
    }

#pragma unroll
    for (int i = 0; i < 4; ++i) {
#pragma unroll
        for (int j = 0; j < 4; ++j) {
            int col = n0 + wn*64 + j*16 + lo;
            int which = col >> 10, cc = col & 1023;
            int h_ = cc >> 6, d_ = cc & 63;
            ushort* dst = (which == 0) ? Qo : (which == 1) ? Ko : Vo;
#pragma unroll
            for (int r = 0; r < 4; ++r) {
                int row = m0 + wm*64 + i*16 + hi*4 + r;
                int b_ = row >> 11, n_ = row & 2047;
                dst[(((size_t)(b_*HEADS + h_))*SEQ + n_)*DHEAD + d_] = f2bf(acc[i][j][r]);
            }
        }
    }
}

// ---------------- flash attention: Q,K,V [B*H][N][D] bf16 -> out [B][N][H*D] bf16 ----------------
__global__ __launch_bounds__(256) void attn_kernel(
    const ushort* __restrict__ Q, const ushort* __restrict__ K,
    const ushort* __restrict__ V, ushort* __restrict__ O) {
    int t = threadIdx.x;
    int lane = t & 63, wid = t >> 6;
    int lo = lane & 15, hi = lane >> 4;
    int bh = blockIdx.x >> 3;          // b*16+h
    int qb = blockIdx.x & 7;
    int q0 = qb * 256 + wid * 64;      // this wave's 64 q rows

    const ushort* Qbh = Q + (size_t)bh * SEQ * DHEAD;
    const ushort* Kbh = K + (size_t)bh * SEQ * DHEAD;
    const ushort* Vbh = V + (size_t)bh * SEQ * DHEAD;

    short8 qf[4][2];
#pragma unroll
    for (int qt = 0; qt < 4; ++qt)
#pragma unroll
        for (int c = 0; c < 2; ++c)
            qf[qt][c] = *(const short8*)(Qbh + (size_t)(q0 + qt*16 + lo)*DHEAD + c*32 + hi*8);

    f32x4 oacc[4][4];
#pragma unroll
    for (int qt = 0; qt < 4; ++qt)
#pragma unroll
        for (int dt = 0; dt < 4; ++dt) oacc[qt][dt] = (f32x4){0.f,0.f,0.f,0.f};
    float m_[4], l_[4];
#pragma unroll
    for (int qt = 0; qt < 4; ++qt) { m_[qt] = -1e30f; l_[qt] = 0.f; }

    for (int kb = 0; kb < SEQ/32; ++kb) {
        short8 kf[2][2];
#pragma unroll
        for (int kt = 0; kt < 2; ++kt)
#pragma unroll
            for (int c = 0; c < 2; ++c)
                kf[kt][c] = *(const short8*)(Kbh + (size_t)(kb*32 + kt*16 + lo)*DHEAD + c*32 + hi*8);

        // V gather: slot j holds row kappa(hi,j) = hi*4 + (j&3) + 16*(j>>2), col dt*16+lo
        short8 vf[4];
#pragma unroll
        for (int dt = 0; dt < 4; ++dt) {
            short8 v;
#pragma unroll
            for (int j = 0; j < 8; ++j) {
                int kr = hi*4 + (j & 3) + 16*(j >> 2);
                v[j] = (short)Vbh[(size_t)(kb*32 + kr)*DHEAD + dt*16 + lo];
            }
            vf[dt] = v;
        }

#pragma unroll
        for (int qt = 0; qt < 4; ++qt) {
            f32x4 s[2];
#pragma unroll
            for (int kt = 0; kt < 2; ++kt) {
                f32x4 z = (f32x4){0.f,0.f,0.f,0.f};
                z = __builtin_amdgcn_mfma_f32_16x16x32_bf16(kf[kt][0], qf[qt][0], z, 0, 0, 0);
                z = __builtin_amdgcn_mfma_f32_16x16x32_bf16(kf[kt][1], qf[qt][1], z, 0, 0, 0);
                s[kt] = z;
            }
            float tmax = -1e30f;
#pragma unroll
            for (int kt = 0; kt < 2; ++kt)
#pragma unroll
                for (int r = 0; r < 4; ++r) {
                    s[kt][r] *= SCALE;
                    tmax = fmaxf(tmax, s[kt][r]);
                }
            tmax = fmaxf(tmax, __shfl_xor(tmax, 16, 64));
            tmax = fmaxf(tmax, __shfl_xor(tmax, 32, 64));
            float mn = fmaxf(m_[qt], tmax);
            float sc_old = __expf(m_[qt] - mn);
            m_[qt] = mn;
            float ts = 0.f;
            short8 pb;
#pragma unroll
            for (int kt = 0; kt < 2; ++kt)
#pragma unroll
                for (int r = 0; r < 4; ++r) {
                    float p = __expf(s[kt][r] - mn);
                    ts += p;
                    pb[kt*4 + r] = (short)f2bf(p);
                }
            ts += __shfl_xor(ts, 16, 64);
            ts += __shfl_xor(ts, 32, 64);
            l_[qt] = l_[qt]*sc_old + ts;
#pragma unroll
            for (int dt = 0; dt < 4; ++dt) {
                f32x4 o = oacc[qt][dt];
#pragma unroll
                for (int r = 0; r < 4; ++r) o[r] *= sc_old;
                oacc[qt][dt] = __builtin_amdgcn_mfma_f32_16x16x32_bf16(vf[dt], pb, o, 0, 0, 0);
            }
        }
    }

    int b_ = bh >> 4, h_ = bh & 15;
#pragma unroll
    for (int qt = 0; qt < 4; ++qt) {
        float inv = 1.0f / l_[qt];
        int n_ = q0 + qt*16 + lo;
        ushort* dst = O + ((size_t)(b_*SEQ + n_))*DIM + h_*DHEAD;
#pragma unroll
        for (int dt = 0; dt < 4; ++dt)
#pragma unroll
            for (int r = 0; r < 4; ++r)
                dst[dt*16 + hi*4 + r] = f2bf(oacc[qt][dt][r] * inv);
    }
}

// ---------------- GEMM2: ao[8192][1024] @ woutT[1024][1024]^T + bias -> fp32 out ----------------
__global__ __launch_bounds__(256) void gemm2_kernel(
    const ushort* __restrict__ A, const ushort* __restrict__ BT,
    const float* __restrict__ bias, float* __restrict__ Cout) {
    const int K = DIM;
    __shared__ ushort As[128][32];
    __shared__ ushort Bs[128][32];
    int t = threadIdx.x;
    int lane = t & 63, wid = t >> 6;
    int lo = lane & 15, hi = lane >> 4;
    int wm = wid >> 1, wn = wid & 1;
    int bx = blockIdx.x % (DIM/128), by = blockIdx.x / (DIM/128);
    int m0 = by * 128, n0 = bx * 128;
    int sr = t >> 2, sc = (t & 3) * 8;

    const ushort* ga = A  + (size_t)m0 * K + sc;
    const ushort* gb = BT + (size_t)n0 * K + sc;

    f32x4 acc[4][4];
#pragma unroll
    for (int i = 0; i < 4; ++i)
#pragma unroll
        for (int j = 0; j < 4; ++j) acc[i][j] = (f32x4){0.f,0.f,0.f,0.f};

    for (int k0 = 0; k0 < K; k0 += 32) {
        short8 a0 = *(const short8*)(ga + (size_t)sr*K + k0);
        short8 a1 = *(const short8*)(ga + (size_t)(sr+64)*K + k0);
        short8 b0 = *(const short8*)(gb + (size_t)sr*K + k0);
        short8 b1 = *(const short8*)(gb + (size_t)(sr+64)*K + k0);
        __syncthreads();
        *(short8*)&As[sr][sc]    = a0;
        *(short8*)&As[sr+64][sc] = a1;
        *(short8*)&Bs[sr][sc]    = b0;
        *(short8*)&Bs[sr+64][sc] = b1;
        __syncthreads();
        short8 af[4], bf[4];
#pragma unroll
        for (int i = 0; i < 4; ++i) af[i] = *(const short8*)&As[wm*64 + i*16 + lo][hi*8];
#pragma unroll
        for (int j = 0; j < 4; ++j) bf[j] = *(const short8*)&Bs[wn*64 + j*16 + lo][hi*8];
#pragma unroll
        for (int i = 0; i < 4; ++i)
#pragma unroll
            for (int j = 0; j < 4; ++j)
                acc[i][j] = __builtin_amdgcn_mfma_f32_16x16x32_bf16(af[i], bf[j], acc[i][j], 0, 0, 0);
    }

#pragma unroll
    for (int i = 0; i < 4; ++i)
#pragma unroll
        for (int j = 0; j < 4; ++j) {
            int col = n0 + wn*64 + j*16 + lo;
            float bv = bias[col];
#pragma unroll
            for (int r = 0; r < 4; ++r) {
                int row = m0 + wm*64 + i*16 + hi*4 + r;
                Cout[(size_t)row*DIM + col] = acc[i][j][r] + bv;
            }
        }
}

extern "C" void kernel_launch(void* const* d_in, const int* in_sizes, int n_in,
                              void* d_out, int out_size, void* d_ws, size_t ws_size,
                              hipStream_t stream) {
    const float* x     = (const float*)d_in[0];
    const float* w_qkv = (const float*)d_in[1];
    const float* w_out = (const float*)d_in[2];
    const float* b_out = (const float*)d_in[3];
    float* out = (float*)d_out;

    char* ws = (char*)d_ws;
    ushort* xb    = (ushort*)(ws);                        // 16 MB  [8192][1024]
    ushort* wqkvT = (ushort*)(ws + ((size_t)16 << 20));   //  6 MB  [3072][1024]
    ushort* woutT = (ushort*)(ws + ((size_t)22 << 20));   //  2 MB  [1024][1024]
    ushort* q     = (ushort*)(ws + ((size_t)24 << 20));   // 16 MB  [B*H][N][D]
    ushort* k     = (ushort*)(ws + ((size_t)40 << 20));   // 16 MB
    ushort* v     = (ushort*)(ws + ((size_t)56 << 20));   // 16 MB
    ushort* ao    = (ushort*)(ws + ((size_t)72 << 20));   // 16 MB  [B][N][H*D]

    cvt_x_kernel<<<(ROWS*DIM/8)/256, 256, 0, stream>>>(x, xb, ROWS*DIM/8);
    transpose_w_kernel<<<(NQKV/32)*(DIM/32), 256, 0, stream>>>(w_qkv, wqkvT, DIM, NQKV);
    transpose_w_kernel<<<(DIM/32)*(DIM/32), 256, 0, stream>>>(w_out, woutT, DIM, DIM);
    gemm1_kernel<<<(NQKV/128)*(ROWS/128), 256, 0, stream>>>(xb, wqkvT, q, k, v);
    attn_kernel<<<(BATCH*HEADS)*(SEQ/256), 256, 0, stream>>>(q, k, v, ao);
    gemm2_kernel<<<(DIM/128)*(ROWS/128), 256, 0, stream>>>(ao, woutT, b_out, out);
}

// Round 2
// 277.686 us; speedup vs baseline: 1.0553x; 1.0553x over previous
//
#include <hip/hip_runtime.h>
#include <hip/hip_bf16.h>
#include <stdint.h>

#define BATCH 4
#define SEQ   2048
#define HEADS 16
#define DHEAD 64
#define DIM   1024
#define NQKV  3072
#define ROWS  (BATCH*SEQ)   // 8192
// SCALE * log2(e): QK^T pre-scaled into Q so softmax is pure exp2
#define QSCALE 0.18033688011112042f

typedef __attribute__((ext_vector_type(8))) short short8;
typedef __attribute__((ext_vector_type(4))) float f32x4;
typedef __attribute__((ext_vector_type(2))) int int2v;

#if __has_builtin(__builtin_amdgcn_exp2f)
#define EXP2F(x) __builtin_amdgcn_exp2f(x)
#else
#define EXP2F(x) __expf((x) * 0.6931471805599453f)
#endif

__device__ __forceinline__ ushort f2bf(float f) {
    union { float f; uint32_t u; } x; x.f = f;
    uint32_t r = x.u + 0x7fffu + ((x.u >> 16) & 1u);
    return (ushort)(r >> 16);
}

// ---------------- cast x (fp32 -> bf16), 8 elems/thread ----------------
__global__ __launch_bounds__(256) void cvt_x_kernel(
    const float* __restrict__ in, ushort* __restrict__ out, int n8) {
    int i = blockIdx.x * 256 + threadIdx.x;
    if (i >= n8) return;
    f32x4 a = ((const f32x4*)in)[2*i];
    f32x4 b = ((const f32x4*)in)[2*i+1];
    short8 o;
    o[0]=(short)f2bf(a[0]); o[1]=(short)f2bf(a[1]); o[2]=(short)f2bf(a[2]); o[3]=(short)f2bf(a[3]);
    o[4]=(short)f2bf(b[0]); o[5]=(short)f2bf(b[1]); o[6]=(short)f2bf(b[2]); o[7]=(short)f2bf(b[3]);
    ((short8*)out)[i] = o;
}

// ---------------- transpose weights: in[R][C] f32 -> out[C][R] bf16 ----------------
__global__ __launch_bounds__(256) void transpose_w_kernel(
    const float* __restrict__ in, ushort* __restrict__ out, int R, int C) {
    __shared__ float tile[32][33];
    int ctiles = C >> 5;
    int bx = blockIdx.x % ctiles, by = blockIdx.x / ctiles;
    int c0 = bx << 5, r0 = by << 5;
    int tx = threadIdx.x & 31, ty = threadIdx.x >> 5;   // ty: 0..7
#pragma unroll
    for (int it = 0; it < 4; ++it)
        tile[ty + 8*it][tx] = in[(size_t)(r0 + ty + 8*it)*C + c0 + tx];
    __syncthreads();
#pragma unroll
    for (int it = 0; it < 4; ++it)
        out[(size_t)(c0 + ty + 8*it)*R + r0 + tx] = f2bf(tile[tx][ty + 8*it]);
}

// ---------------- GEMM1: xb[8192][1024] @ wqkvT[3072][1024]^T -> Q/K/V bf16 ----------------
// Q is pre-scaled by QSCALE so attention softmax works directly in exp2 domain.
__global__ __launch_bounds__(256) void gemm1_kernel(
    const ushort* __restrict__ A, const ushort* __restrict__ BT,
    ushort* __restrict__ Qo, ushort* __restrict__ Ko, ushort* __restrict__ Vo) {
    const int K = DIM;
    __shared__ ushort As[128][32];
    __shared__ ushort Bs[128][32];
    int t = threadIdx.x;
    int lane = t & 63, wid = t >> 6;
    int lo = lane & 15, hi = lane >> 4;
    int wm = wid >> 1, wn = wid & 1;
    int bx = blockIdx.x % (NQKV/128), by = blockIdx.x / (NQKV/128);
    int m0 = by * 128, n0 = bx * 128;
    int sr = t >> 2, sc = (t & 3) * 8;

    const ushort* ga = A  + (size_t)m0 * K + sc;
    const ushort* gb = BT + (size_t)n0 * K + sc;

    f32x4 acc[4][4];
#pragma unroll
    for (int i = 0; i < 4; ++i)
#pragma unroll
        for (int j = 0; j < 4; ++j) acc[i][j] = (f32x4){0.f,0.f,0.f,0.f};

    for (int k0 = 0; k0 < K; k0 += 32) {
        short8 a0 = *(const short8*)(ga + (size_t)sr*K + k0);
        short8 a1 = *(const short8*)(ga + (size_t)(sr+64)*K + k0);
        short8 b0 = *(const short8*)(gb + (size_t)sr*K + k0);
        short8 b1 = *(const short8*)(gb + (size_t)(sr+64)*K + k0);
        __syncthreads();
        *(short8*)&As[sr][sc]    = a0;
        *(short8*)&As[sr+64][sc] = a1;
        *(short8*)&Bs[sr][sc]    = b0;
        *(short8*)&Bs[sr+64][sc] = b1;
        __syncthreads();
        short8 af[4], bf[4];
#pragma unroll
        for (int i = 0; i < 4; ++i) af[i] = *(const short8*)&As[wm*64 + i*16 + lo][hi*8];
#pragma unroll
        for (int j = 0; j < 4; ++j) bf[j] = *(const short8*)&Bs[wn*64 + j*16 + lo][hi*8];
#pragma unroll
        for (int i = 0; i < 4; ++i)
#pragma unroll
            for (int j = 0; j < 4; ++j)
                acc[i][j] = __builtin_amdgcn_mfma_f32_16x16x32_bf16(af[i], bf[j], acc[i][j], 0, 0, 0);
    }

#pragma unroll
    for (int i = 0; i < 4; ++i) {
#pragma unroll
        for (int j = 0; j < 4; ++j) {
            int col = n0 + wn*64 + j*16 + lo;
            int which = col >> 10, cc = col & 1023;
            int h_ = cc >> 6, d_ = cc & 63;
            ushort* dst = (which == 0) ? Qo : (which == 1) ? Ko : Vo;
            float scl = (which == 0) ? QSCALE : 1.0f;
#pragma unroll
            for (int r = 0; r < 4; ++r) {
                int row = m0 + wm*64 + i*16 + hi*4 + r;
                int b_ = row >> 11, n_ = row & 2047;
                dst[(((size_t)(b_*HEADS + h_))*SEQ + n_)*DHEAD + d_] = f2bf(acc[i][j][r] * scl);
            }
        }
    }
}

// ---------------- flash attention ----------------
// Q,K,V [B*H][N][D] bf16 -> out [B][N][H*D] bf16
// K staged in LDS with XOR swizzle (conflict-free ds_read_b128 fragments);
// V staged in LDS subtiled [4 colgrp][16 rowgrp][4][16] for ds_read_b64_tr_b16.
#define TR16(dst, addr, imm) \
    asm volatile("ds_read_b64_tr_b16 %0, %1 offset:%c2" : "=v"(dst) : "v"(addr), "n"(imm))

__global__ __launch_bounds__(256) void attn_kernel(
    const ushort* __restrict__ Q, const ushort* __restrict__ K,
    const ushort* __restrict__ V, ushort* __restrict__ O) {
    __shared__ ushort Ks[2][4096];   // [64 rows][64 cols] swizzled, 8KB per buf
    __shared__ ushort Vs[2][4096];   // [4][16][4][16] subtiled, 8KB per buf

    int t = threadIdx.x;
    int lane = t & 63, wid = t >> 6;
    int lo = lane & 15, hi = lane >> 4;
    // XCD-aware: all 8 q-blocks of one bh land on the same XCD (bid%8 == bh%8)
    int bid = blockIdx.x;
    int bh = bid & 63, qb = bid >> 6;
    int q0 = qb * 256 + wid * 64;

    const ushort* Qbh = Q + (size_t)bh * SEQ * DHEAD;
    const ushort* Kbh = K + (size_t)bh * SEQ * DHEAD;
    const ushort* Vbh = V + (size_t)bh * SEQ * DHEAD;

    short8 qf[4][2];
#pragma unroll
    for (int qt = 0; qt < 4; ++qt)
#pragma unroll
        for (int c = 0; c < 2; ++c)
            qf[qt][c] = *(const short8*)(Qbh + (size_t)(q0 + qt*16 + lo)*DHEAD + c*32 + hi*8);

    f32x4 oacc[4][4];
#pragma unroll
    for (int qt = 0; qt < 4; ++qt)
#pragma unroll
        for (int dt = 0; dt < 4; ++dt) oacc[qt][dt] = (f32x4){0.f,0.f,0.f,0.f};
    float m_[4], l_[4];
#pragma unroll
    for (int qt = 0; qt < 4; ++qt) { m_[qt] = -1e30f; l_[qt] = 0.f; }

    uint32_t vbase0 = (uint32_t)(uintptr_t)(&Vs[0][0]) + ((uint32_t)lane << 3);

    int rr = t >> 3, c8 = t & 7;   // staging coords: row rr(+32i), col chunk c8
    short8 kreg[2], vreg[2];

#define GLOAD(KB) do { \
    _Pragma("unroll") \
    for (int i = 0; i < 2; ++i) { \
        int r = i*32 + rr; \
        kreg[i] = *(const short8*)(Kbh + ((size_t)((KB)*64 + r))*64 + c8*8); \
        vreg[i] = *(const short8*)(Vbh + ((size_t)((KB)*64 + r))*64 + c8*8); \
    } } while(0)
#define SWRITE(BUF) do { \
    _Pragma("unroll") \
    for (int i = 0; i < 2; ++i) { \
        int r = i*32 + rr; \
        *(short8*)((char*)&Ks[BUF][0] + r*128 + ((c8*16) ^ ((rr&7)<<4))) = kreg[i]; \
        *(short8*)&Vs[BUF][(c8>>1)*1024 + (r>>2)*64 + (r&3)*16 + (c8&1)*8] = vreg[i]; \
    } } while(0)

    GLOAD(0); SWRITE(0);
    int cur = 0;
    for (int kb = 0; kb < SEQ/64; ++kb) {
        __syncthreads();
        if (kb+1 < SEQ/64) GLOAD(kb+1);     // issue-early; write-late (T14)
        const char* ksb = (const char*)&Ks[cur][0];
        uint32_t vab = vbase0 + (uint32_t)cur * 8192u;
#pragma unroll
        for (int s = 0; s < 2; ++s) {
            short8 kf[2][2];
#pragma unroll
            for (int kt = 0; kt < 2; ++kt)
#pragma unroll
                for (int c = 0; c < 2; ++c)
                    kf[kt][c] = *(const short8*)(ksb + (s*32 + kt*16 + lo)*128
                                                 + (((c*4 + hi) ^ (lo & 7)) << 4));
            uint32_t va = vab + (uint32_t)s * 1024u;
            int2v t00,t01,t10,t11,t20,t21,t30,t31;
            TR16(t00, va, 0);    TR16(t01, va, 512);
            TR16(t10, va, 2048); TR16(t11, va, 2560);
            TR16(t20, va, 4096); TR16(t21, va, 4608);
            TR16(t30, va, 6144); TR16(t31, va, 6656);
            asm volatile("s_waitcnt lgkmcnt(0)" ::: "memory");
            __builtin_amdgcn_sched_barrier(0);
            union VU { int2v i2[2]; short8 s8; };
            short8 vf[4];
            { VU u; u.i2[0]=t00; u.i2[1]=t01; vf[0]=u.s8; }
            { VU u; u.i2[0]=t10; u.i2[1]=t11; vf[1]=u.s8; }
            { VU u; u.i2[0]=t20; u.i2[1]=t21; vf[2]=u.s8; }
            { VU u; u.i2[0]=t30; u.i2[1]=t31; vf[3]=u.s8; }

#pragma unroll
            for (int qt = 0; qt < 4; ++qt) {
                f32x4 s0 = (f32x4){0.f,0.f,0.f,0.f}, s1 = (f32x4){0.f,0.f,0.f,0.f};
                s0 = __builtin_amdgcn_mfma_f32_16x16x32_bf16(kf[0][0], qf[qt][0], s0, 0, 0, 0);
                s0 = __builtin_amdgcn_mfma_f32_16x16x32_bf16(kf[0][1], qf[qt][1], s0, 0, 0, 0);
                s1 = __builtin_amdgcn_mfma_f32_16x16x32_bf16(kf[1][0], qf[qt][0], s1, 0, 0, 0);
                s1 = __builtin_amdgcn_mfma_f32_16x16x32_bf16(kf[1][1], qf[qt][1], s1, 0, 0, 0);
                float tmax = s0[0];
                tmax = fmaxf(tmax, s0[1]); tmax = fmaxf(tmax, s0[2]); tmax = fmaxf(tmax, s0[3]);
                tmax = fmaxf(tmax, s1[0]); tmax = fmaxf(tmax, s1[1]);
                tmax = fmaxf(tmax, s1[2]); tmax = fmaxf(tmax, s1[3]);
                tmax = fmaxf(tmax, __shfl_xor(tmax, 16, 64));
                tmax = fmaxf(tmax, __shfl_xor(tmax, 32, 64));
                if (__ballot(tmax > m_[qt] + 8.0f)) {   // defer-max (T13)
                    float mn = fmaxf(m_[qt], tmax);
                    float sc = EXP2F(m_[qt] - mn);
                    m_[qt] = mn; l_[qt] *= sc;
#pragma unroll
                    for (int dt = 0; dt < 4; ++dt)
#pragma unroll
                        for (int r = 0; r < 4; ++r) oacc[qt][dt][r] *= sc;
                }
                float pv[8];
                float mm = m_[qt];
                pv[0]=EXP2F(s0[0]-mm); pv[1]=EXP2F(s0[1]-mm); pv[2]=EXP2F(s0[2]-mm); pv[3]=EXP2F(s0[3]-mm);
                pv[4]=EXP2F(s1[0]-mm); pv[5]=EXP2F(s1[1]-mm); pv[6]=EXP2F(s1[2]-mm); pv[7]=EXP2F(s1[3]-mm);
                float ts = ((pv[0]+pv[1])+(pv[2]+pv[3])) + ((pv[4]+pv[5])+(pv[6]+pv[7]));
                ts += __shfl_xor(ts, 16, 64);
                ts += __shfl_xor(ts, 32, 64);
                l_[qt] += ts;
                union PU { uint32_t u[4]; short8 s8; } pu;
                asm("v_cvt_pk_bf16_f32 %0, %1, %2" : "=v"(pu.u[0]) : "v"(pv[0]), "v"(pv[1]));
                asm("v_cvt_pk_bf16_f32 %0, %1, %2" : "=v"(pu.u[1]) : "v"(pv[2]), "v"(pv[3]));
                asm("v_cvt_pk_bf16_f32 %0, %1, %2" : "=v"(pu.u[2]) : "v"(pv[4]), "v"(pv[5]));
                asm("v_cvt_pk_bf16_f32 %0, %1, %2" : "=v"(pu.u[3]) : "v"(pv[6]), "v"(pv[7]));
#pragma unroll
                for (int dt = 0; dt < 4; ++dt)
                    oacc[qt][dt] = __builtin_amdgcn_mfma_f32_16x16x32_bf16(vf[dt], pu.s8, oacc[qt][dt], 0, 0, 0);
            }
        }
        if (kb+1 < SEQ/64) SWRITE(cur^1);
        cur ^= 1;
    }

    int b_ = bh >> 4, h_ = bh & 15;
#pragma unroll
    for (int qt = 0; qt < 4; ++qt) {
        float inv = 1.0f / l_[qt];
        int n_ = q0 + qt*16 + lo;
        ushort* dst = O + ((size_t)(b_*SEQ + n_))*DIM + h_*DHEAD;
#pragma unroll
        for (int dt = 0; dt < 4; ++dt)
#pragma unroll
            for (int r = 0; r < 4; ++r)
                dst[dt*16 + hi*4 + r] = f2bf(oacc[qt][dt][r] * inv);
    }
}

// ---------------- GEMM2: ao[8192][1024] @ woutT[1024][1024]^T + bias -> fp32 out ----------------
__global__ __launch_bounds__(256) void gemm2_kernel(
    const ushort* __restrict__ A, const ushort* __restrict__ BT,
    const float* __restrict__ bias, float* __restrict__ Cout) {
    const int K = DIM;
    __shared__ ushort As[128][32];
    __shared__ ushort Bs[128][32];
    int t = threadIdx.x;
    int lane = t & 63, wid = t >> 6;
    int lo = lane & 15, hi = lane >> 4;
    int wm = wid >> 1, wn = wid & 1;
    int bx = blockIdx.x % (DIM/128), by = blockIdx.x / (DIM/128);
    int m0 = by * 128, n0 = bx * 128;
    int sr = t >> 2, sc = (t & 3) * 8;

    const ushort* ga = A  + (size_t)m0 * K + sc;
    const ushort* gb = BT + (size_t)n0 * K + sc;

    f32x4 acc[4][4];
#pragma unroll
    for (int i = 0; i < 4; ++i)
#pragma unroll
        for (int j = 0; j < 4; ++j) acc[i][j] = (f32x4){0.f,0.f,0.f,0.f};

    for (int k0 = 0; k0 < K; k0 += 32) {
        short8 a0 = *(const short8*)(ga + (size_t)sr*K + k0);
        short8 a1 = *(const short8*)(ga + (size_t)(sr+64)*K + k0);
        short8 b0 = *(const short8*)(gb + (size_t)sr*K + k0);
        short8 b1 = *(const short8*)(gb + (size_t)(sr+64)*K + k0);
        __syncthreads();
        *(short8*)&As[sr][sc]    = a0;
        *(short8*)&As[sr+64][sc] = a1;
        *(short8*)&Bs[sr][sc]    = b0;
        *(short8*)&Bs[sr+64][sc] = b1;
        __syncthreads();
        short8 af[4], bf[4];
#pragma unroll
        for (int i = 0; i < 4; ++i) af[i] = *(const short8*)&As[wm*64 + i*16 + lo][hi*8];
#pragma unroll
        for (int j = 0; j < 4; ++j) bf[j] = *(const short8*)&Bs[wn*64 + j*16 + lo][hi*8];
#pragma unroll
        for (int i = 0; i < 4; ++i)
#pragma unroll
            for (int j = 0; j < 4; ++j)
                acc[i][j] = __builtin_amdgcn_mfma_f32_16x16x32_bf16(af[i], bf[j], acc[i][j], 0, 0, 0);
    }

#pragma unroll
    for (int i = 0; i < 4; ++i)
#pragma unroll
        for (int j = 0; j < 4; ++j) {
            int col = n0 + wn*64 + j*16 + lo;
            float bv = bias[col];
#pragma unroll
            for (int r = 0; r < 4; ++r) {
                int row = m0 + wm*64 + i*16 + hi*4 + r;
                Cout[(size_t)row*DIM + col] = acc[i][j][r] + bv;
            }
        }
}

extern "C" void kernel_launch(void* const* d_in, const int* in_sizes, int n_in,
                              void* d_out, int out_size, void* d_ws, size_t ws_size,
                              hipStream_t stream) {
    const float* x     = (const float*)d_in[0];
    const float* w_qkv = (const float*)d_in[1];
    const float* w_out = (const float*)d_in[2];
    const float* b_out = (const float*)d_in[3];
    float* out = (float*)d_out;

    char* ws = (char*)d_ws;
    ushort* xb    = (ushort*)(ws);                        // 16 MB  [8192][1024]
    ushort* wqkvT = (ushort*)(ws + ((size_t)16 << 20));   //  6 MB  [3072][1024]
    ushort* woutT = (ushort*)(ws + ((size_t)22 << 20));   //  2 MB  [1024][1024]
    ushort* q     = (ushort*)(ws + ((size_t)24 << 20));   // 16 MB  [B*H][N][D]
    ushort* k     = (ushort*)(ws + ((size_t)40 << 20));   // 16 MB
    ushort* v     = (ushort*)(ws + ((size_t)56 << 20));   // 16 MB
    ushort* ao    = (ushort*)(ws + ((size_t)72 << 20));   // 16 MB  [B][N][H*D]

    cvt_x_kernel<<<(ROWS*DIM/8)/256, 256, 0, stream>>>(x, xb, ROWS*DIM/8);
    transpose_w_kernel<<<(NQKV/32)*(DIM/32), 256, 0, stream>>>(w_qkv, wqkvT, DIM, NQKV);
    transpose_w_kernel<<<(DIM/32)*(DIM/32), 256, 0, stream>>>(w_out, woutT, DIM, DIM);
    gemm1_kernel<<<(NQKV/128)*(ROWS/128), 256, 0, stream>>>(xb, wqkvT, q, k, v);
    attn_kernel<<<(BATCH*HEADS)*(SEQ/256), 256, 0, stream>>>(q, k, v, ao);
    gemm2_kernel<<<(DIM/128)*(ROWS/128), 256, 0, stream>>>(ao, woutT, b_out, out);
}

// Round 3
// 264.182 us; speedup vs baseline: 1.1092x; 1.0511x over previous
//
#include <hip/hip_runtime.h>
#include <hip/hip_bf16.h>
#include <stdint.h>

#define BATCH 4
#define SEQ   2048
#define HEADS 16
#define DHEAD 64
#define DIM   1024
#define NQKV  3072
#define ROWS  (BATCH*SEQ)   // 8192
// SCALE * log2(e): QK^T pre-scaled into Q so softmax is pure exp2
#define QSCALE 0.18033688011112042f

typedef __attribute__((ext_vector_type(8))) short short8;
typedef __attribute__((ext_vector_type(4))) float f32x4;
typedef __attribute__((ext_vector_type(2))) int int2v;

#if __has_builtin(__builtin_amdgcn_exp2f)
#define EXP2F(x) __builtin_amdgcn_exp2f(x)
#else
#define EXP2F(x) __expf((x) * 0.6931471805599453f)
#endif

typedef const __attribute__((address_space(1))) uint32_t GU32;
typedef __attribute__((address_space(3))) uint32_t LU32;
#define GLLDS16(g, l) __builtin_amdgcn_global_load_lds((GU32*)(g), (LU32*)(l), 16, 0, 0)

__device__ __forceinline__ ushort f2bf(float f) {
    union { float f; uint32_t u; } x; x.f = f;
    uint32_t r = x.u + 0x7fffu + ((x.u >> 16) & 1u);
    return (ushort)(r >> 16);
}

// ---------------- cast x (fp32 -> bf16), 8 elems/thread ----------------
__global__ __launch_bounds__(256) void cvt_x_kernel(
    const float* __restrict__ in, ushort* __restrict__ out, int n8) {
    int i = blockIdx.x * 256 + threadIdx.x;
    if (i >= n8) return;
    f32x4 a = ((const f32x4*)in)[2*i];
    f32x4 b = ((const f32x4*)in)[2*i+1];
    short8 o;
    o[0]=(short)f2bf(a[0]); o[1]=(short)f2bf(a[1]); o[2]=(short)f2bf(a[2]); o[3]=(short)f2bf(a[3]);
    o[4]=(short)f2bf(b[0]); o[5]=(short)f2bf(b[1]); o[6]=(short)f2bf(b[2]); o[7]=(short)f2bf(b[3]);
    ((short8*)out)[i] = o;
}

// ---------------- transpose weights: in[R][C] f32 -> out[C][R] bf16 ----------------
__global__ __launch_bounds__(256) void transpose_w_kernel(
    const float* __restrict__ in, ushort* __restrict__ out, int R, int C) {
    __shared__ float tile[32][33];
    int ctiles = C >> 5;
    int bx = blockIdx.x % ctiles, by = blockIdx.x / ctiles;
    int c0 = bx << 5, r0 = by << 5;
    int tx = threadIdx.x & 31, ty = threadIdx.x >> 5;   // ty: 0..7
#pragma unroll
    for (int it = 0; it < 4; ++it)
        tile[ty + 8*it][tx] = in[(size_t)(r0 + ty + 8*it)*C + c0 + tx];
    __syncthreads();
#pragma unroll
    for (int it = 0; it < 4; ++it)
        out[(size_t)(c0 + ty + 8*it)*R + r0 + tx] = f2bf(tile[tx][ty + 8*it]);
}

// ---------------- GEMM1: xb[8192][1024] @ wqkvT[3072][1024]^T -> Q/K/V bf16 ----------------
// Q is pre-scaled by QSCALE. Staging via global_load_lds width-16 (m97 structure).
__global__ __launch_bounds__(256) void gemm1_kernel(
    const ushort* __restrict__ A, const ushort* __restrict__ BT,
    ushort* __restrict__ Qo, ushort* __restrict__ Ko, ushort* __restrict__ Vo) {
    const int K = DIM;
    __shared__ ushort As[128][32];
    __shared__ ushort Bs[128][32];
    int t = threadIdx.x;
    int lane = t & 63, wid = t >> 6;
    int lo = lane & 15, hi = lane >> 4;
    int wm = wid >> 1, wn = wid & 1;
    int bx = blockIdx.x % (NQKV/128), by = blockIdx.x / (NQKV/128);
    int m0 = by * 128, n0 = bx * 128;
    int sr = t >> 2, sc = (t & 3) * 8;

    const ushort* ga = A  + (size_t)(m0 + sr) * K + sc;
    const ushort* gb = BT + (size_t)(n0 + sr) * K + sc;
    char* asb = (char*)&As[0][0] + wid * 1024;   // wave-uniform LDS dest
    char* bsb = (char*)&Bs[0][0] + wid * 1024;

    f32x4 acc[4][4];
#pragma unroll
    for (int i = 0; i < 4; ++i)
#pragma unroll
        for (int j = 0; j < 4; ++j) acc[i][j] = (f32x4){0.f,0.f,0.f,0.f};

    for (int k0 = 0; k0 < K; k0 += 32) {
        __syncthreads();
        GLLDS16(ga + k0,            asb);
        GLLDS16(ga + (size_t)64*K + k0, asb + 4096);
        GLLDS16(gb + k0,            bsb);
        GLLDS16(gb + (size_t)64*K + k0, bsb + 4096);
        __syncthreads();
        short8 af[4], bf[4];
#pragma unroll
        for (int i = 0; i < 4; ++i) af[i] = *(const short8*)&As[wm*64 + i*16 + lo][hi*8];
#pragma unroll
        for (int j = 0; j < 4; ++j) bf[j] = *(const short8*)&Bs[wn*64 + j*16 + lo][hi*8];
#pragma unroll
        for (int i = 0; i < 4; ++i)
#pragma unroll
            for (int j = 0; j < 4; ++j)
                acc[i][j] = __builtin_amdgcn_mfma_f32_16x16x32_bf16(af[i], bf[j], acc[i][j], 0, 0, 0);
    }

#pragma unroll
    for (int i = 0; i < 4; ++i) {
#pragma unroll
        for (int j = 0; j < 4; ++j) {
            int col = n0 + wn*64 + j*16 + lo;
            int which = col >> 10, cc = col & 1023;
            int h_ = cc >> 6, d_ = cc & 63;
            ushort* dst = (which == 0) ? Qo : (which == 1) ? Ko : Vo;
            float scl = (which == 0) ? QSCALE : 1.0f;
#pragma unroll
            for (int r = 0; r < 4; ++r) {
                int row = m0 + wm*64 + i*16 + hi*4 + r;
                int b_ = row >> 11, n_ = row & 2047;
                dst[(((size_t)(b_*HEADS + h_))*SEQ + n_)*DHEAD + d_] = f2bf(acc[i][j][r] * scl);
            }
        }
    }
}

// ---------------- flash attention ----------------
// Q,K,V [B*H][N][D] bf16 -> out [B][N][H*D] bf16
// K read directly from global (L2-resident: 256KB/head). V staged in LDS
// subtiled [4 colgrp][16 rowgrp][4][16] for ds_read_b64_tr_b16, double-buffered.
// Each wave: 32 q rows; block = 4 waves = 128 q rows; grid = 64 bh x 16 qb.
#define TR16(dst, addr, imm) \
    asm volatile("ds_read_b64_tr_b16 %0, %1 offset:%c2" : "=v"(dst) : "v"(addr), "n"(imm))

__global__ __launch_bounds__(256, 3) void attn_kernel(
    const ushort* __restrict__ Q, const ushort* __restrict__ K,
    const ushort* __restrict__ V, ushort* __restrict__ O) {
    __shared__ ushort Vs[2][4096];   // 8KB per buf

    int t = threadIdx.x;
    int lane = t & 63, wid = t >> 6;
    int lo = lane & 15, hi = lane >> 4;
    // bid%64 = bh: the 16 q-blocks of one head share bid%8 -> same XCD L2
    int bid = blockIdx.x;
    int bh = bid & 63, qb = bid >> 6;
    int q0 = qb * 128 + wid * 32;

    const ushort* Qbh = Q + (size_t)bh * SEQ * DHEAD;
    const ushort* Kbh = K + (size_t)bh * SEQ * DHEAD;
    const ushort* Vbh = V + (size_t)bh * SEQ * DHEAD;

    short8 qf[2][2];
#pragma unroll
    for (int qt = 0; qt < 2; ++qt)
#pragma unroll
        for (int c = 0; c < 2; ++c)
            qf[qt][c] = *(const short8*)(Qbh + (size_t)(q0 + qt*16 + lo)*DHEAD + c*32 + hi*8);

    f32x4 oacc[2][4];
#pragma unroll
    for (int qt = 0; qt < 2; ++qt)
#pragma unroll
        for (int dt = 0; dt < 4; ++dt) oacc[qt][dt] = (f32x4){0.f,0.f,0.f,0.f};
    float m_[2], l_[2];
#pragma unroll
    for (int qt = 0; qt < 2; ++qt) { m_[qt] = -1e30f; l_[qt] = 0.f; }

    uint32_t vbase0 = (uint32_t)(uintptr_t)(&Vs[0][0]) + ((uint32_t)lane << 3);

    int rr = t >> 3, c8 = t & 7;   // V staging coords
    short8 vreg[2];

#define GLOADV(KB) do { \
    _Pragma("unroll") \
    for (int i = 0; i < 2; ++i) { \
        int r = i*32 + rr; \
        vreg[i] = *(const short8*)(Vbh + ((size_t)((KB)*64 + r))*64 + c8*8); \
    } } while(0)
#define SWRITEV(BUF) do { \
    _Pragma("unroll") \
    for (int i = 0; i < 2; ++i) { \
        int r = i*32 + rr; \
        *(short8*)&Vs[BUF][(c8>>1)*1024 + (r>>2)*64 + (r&3)*16 + (c8&1)*8] = vreg[i]; \
    } } while(0)

    GLOADV(0); SWRITEV(0);
    int cur = 0;
    for (int kb = 0; kb < SEQ/64; ++kb) {
        __syncthreads();
        // K fragments for the whole 64-row tile, straight from global (L2)
        short8 kf[2][2][2];
#pragma unroll
        for (int s = 0; s < 2; ++s)
#pragma unroll
            for (int kt = 0; kt < 2; ++kt)
#pragma unroll
                for (int c = 0; c < 2; ++c)
                    kf[s][kt][c] = *(const short8*)(Kbh
                        + (size_t)(kb*64 + s*32 + kt*16 + lo)*DHEAD + c*32 + hi*8);
        if (kb+1 < SEQ/64) GLOADV(kb+1);     // V prefetch stays in flight
        uint32_t vab = vbase0 + (uint32_t)cur * 8192u;
#pragma unroll
        for (int s = 0; s < 2; ++s) {
            uint32_t va = vab + (uint32_t)s * 1024u;
            int2v t00,t01,t10,t11,t20,t21,t30,t31;
            TR16(t00, va, 0);    TR16(t01, va, 512);
            TR16(t10, va, 2048); TR16(t11, va, 2560);
            TR16(t20, va, 4096); TR16(t21, va, 4608);
            TR16(t30, va, 6144); TR16(t31, va, 6656);
            asm volatile("s_waitcnt lgkmcnt(0)" ::: "memory");
            __builtin_amdgcn_sched_barrier(0);
            union VU { int2v i2[2]; short8 s8; };
            short8 vf[4];
            { VU u; u.i2[0]=t00; u.i2[1]=t01; vf[0]=u.s8; }
            { VU u; u.i2[0]=t10; u.i2[1]=t11; vf[1]=u.s8; }
            { VU u; u.i2[0]=t20; u.i2[1]=t21; vf[2]=u.s8; }
            { VU u; u.i2[0]=t30; u.i2[1]=t31; vf[3]=u.s8; }

#pragma unroll
            for (int qt = 0; qt < 2; ++qt) {
                f32x4 s0 = (f32x4){0.f,0.f,0.f,0.f}, s1 = (f32x4){0.f,0.f,0.f,0.f};
                s0 = __builtin_amdgcn_mfma_f32_16x16x32_bf16(kf[s][0][0], qf[qt][0], s0, 0, 0, 0);
                s0 = __builtin_amdgcn_mfma_f32_16x16x32_bf16(kf[s][0][1], qf[qt][1], s0, 0, 0, 0);
                s1 = __builtin_amdgcn_mfma_f32_16x16x32_bf16(kf[s][1][0], qf[qt][0], s1, 0, 0, 0);
                s1 = __builtin_amdgcn_mfma_f32_16x16x32_bf16(kf[s][1][1], qf[qt][1], s1, 0, 0, 0);
                float tmax = fmaxf(fmaxf(s0[0], s0[1]), s0[2]);
                tmax = fmaxf(fmaxf(tmax, s0[3]), s1[0]);
                tmax = fmaxf(fmaxf(tmax, s1[1]), s1[2]);
                tmax = fmaxf(tmax, s1[3]);
                tmax = fmaxf(tmax, __shfl_xor(tmax, 16, 64));
                tmax = fmaxf(tmax, __shfl_xor(tmax, 32, 64));
                if (__ballot(tmax > m_[qt] + 8.0f)) {   // defer-max (T13)
                    float mn = fmaxf(m_[qt], tmax);
                    float sc = EXP2F(m_[qt] - mn);
                    m_[qt] = mn; l_[qt] *= sc;
#pragma unroll
                    for (int dt = 0; dt < 4; ++dt)
#pragma unroll
                        for (int r = 0; r < 4; ++r) oacc[qt][dt][r] *= sc;
                }
                float pv[8];
                float mm = m_[qt];
                pv[0]=EXP2F(s0[0]-mm); pv[1]=EXP2F(s0[1]-mm); pv[2]=EXP2F(s0[2]-mm); pv[3]=EXP2F(s0[3]-mm);
                pv[4]=EXP2F(s1[0]-mm); pv[5]=EXP2F(s1[1]-mm); pv[6]=EXP2F(s1[2]-mm); pv[7]=EXP2F(s1[3]-mm);
                float ts = ((pv[0]+pv[1])+(pv[2]+pv[3])) + ((pv[4]+pv[5])+(pv[6]+pv[7]));
                ts += __shfl_xor(ts, 16, 64);
                ts += __shfl_xor(ts, 32, 64);
                l_[qt] += ts;
                union PU { uint32_t u[4]; short8 s8; } pu;
                asm("v_cvt_pk_bf16_f32 %0, %1, %2" : "=v"(pu.u[0]) : "v"(pv[0]), "v"(pv[1]));
                asm("v_cvt_pk_bf16_f32 %0, %1, %2" : "=v"(pu.u[1]) : "v"(pv[2]), "v"(pv[3]));
                asm("v_cvt_pk_bf16_f32 %0, %1, %2" : "=v"(pu.u[2]) : "v"(pv[4]), "v"(pv[5]));
                asm("v_cvt_pk_bf16_f32 %0, %1, %2" : "=v"(pu.u[3]) : "v"(pv[6]), "v"(pv[7]));
#pragma unroll
                for (int dt = 0; dt < 4; ++dt)
                    oacc[qt][dt] = __builtin_amdgcn_mfma_f32_16x16x32_bf16(vf[dt], pu.s8, oacc[qt][dt], 0, 0, 0);
            }
        }
        if (kb+1 < SEQ/64) SWRITEV(cur^1);
        cur ^= 1;
    }

    int b_ = bh >> 4, h_ = bh & 15;
#pragma unroll
    for (int qt = 0; qt < 2; ++qt) {
        float inv = 1.0f / l_[qt];
        int n_ = q0 + qt*16 + lo;
        ushort* dst = O + ((size_t)(b_*SEQ + n_))*DIM + h_*DHEAD;
#pragma unroll
        for (int dt = 0; dt < 4; ++dt)
#pragma unroll
            for (int r = 0; r < 4; ++r)
                dst[dt*16 + hi*4 + r] = f2bf(oacc[qt][dt][r] * inv);
    }
}

// ---------------- GEMM2: ao[8192][1024] @ woutT[1024][1024]^T + bias -> fp32 out ----------------
__global__ __launch_bounds__(256) void gemm2_kernel(
    const ushort* __restrict__ A, const ushort* __restrict__ BT,
    const float* __restrict__ bias, float* __restrict__ Cout) {
    const int K = DIM;
    __shared__ ushort As[128][32];
    __shared__ ushort Bs[128][32];
    int t = threadIdx.x;
    int lane = t & 63, wid = t >> 6;
    int lo = lane & 15, hi = lane >> 4;
    int wm = wid >> 1, wn = wid & 1;
    int bx = blockIdx.x % (DIM/128), by = blockIdx.x / (DIM/128);
    int m0 = by * 128, n0 = bx * 128;
    int sr = t >> 2, sc = (t & 3) * 8;

    const ushort* ga = A  + (size_t)(m0 + sr) * K + sc;
    const ushort* gb = BT + (size_t)(n0 + sr) * K + sc;
    char* asb = (char*)&As[0][0] + wid * 1024;
    char* bsb = (char*)&Bs[0][0] + wid * 1024;

    f32x4 acc[4][4];
#pragma unroll
    for (int i = 0; i < 4; ++i)
#pragma unroll
        for (int j = 0; j < 4; ++j) acc[i][j] = (f32x4){0.f,0.f,0.f,0.f};

    for (int k0 = 0; k0 < K; k0 += 32) {
        __syncthreads();
        GLLDS16(ga + k0,                asb);
        GLLDS16(ga + (size_t)64*K + k0, asb + 4096);
        GLLDS16(gb + k0,                bsb);
        GLLDS16(gb + (size_t)64*K + k0, bsb + 4096);
        __syncthreads();
        short8 af[4], bf[4];
#pragma unroll
        for (int i = 0; i < 4; ++i) af[i] = *(const short8*)&As[wm*64 + i*16 + lo][hi*8];
#pragma unroll
        for (int j = 0; j < 4; ++j) bf[j] = *(const short8*)&Bs[wn*64 + j*16 + lo][hi*8];
#pragma unroll
        for (int i = 0; i < 4; ++i)
#pragma unroll
            for (int j = 0; j < 4; ++j)
                acc[i][j] = __builtin_amdgcn_mfma_f32_16x16x32_bf16(af[i], bf[j], acc[i][j], 0, 0, 0);
    }

#pragma unroll
    for (int i = 0; i < 4; ++i)
#pragma unroll
        for (int j = 0; j < 4; ++j) {
            int col = n0 + wn*64 + j*16 + lo;
            float bv = bias[col];
#pragma unroll
            for (int r = 0; r < 4; ++r) {
                int row = m0 + wm*64 + i*16 + hi*4 + r;
                Cout[(size_t)row*DIM + col] = acc[i][j][r] + bv;
            }
        }
}

extern "C" void kernel_launch(void* const* d_in, const int* in_sizes, int n_in,
                              void* d_out, int out_size, void* d_ws, size_t ws_size,
                              hipStream_t stream) {
    const float* x     = (const float*)d_in[0];
    const float* w_qkv = (const float*)d_in[1];
    const float* w_out = (const float*)d_in[2];
    const float* b_out = (const float*)d_in[3];
    float* out = (float*)d_out;

    char* ws = (char*)d_ws;
    ushort* xb    = (ushort*)(ws);                        // 16 MB  [8192][1024]
    ushort* wqkvT = (ushort*)(ws + ((size_t)16 << 20));   //  6 MB  [3072][1024]
    ushort* woutT = (ushort*)(ws + ((size_t)22 << 20));   //  2 MB  [1024][1024]
    ushort* q     = (ushort*)(ws + ((size_t)24 << 20));   // 16 MB  [B*H][N][D]
    ushort* k     = (ushort*)(ws + ((size_t)40 << 20));   // 16 MB
    ushort* v     = (ushort*)(ws + ((size_t)56 << 20));   // 16 MB
    ushort* ao    = (ushort*)(ws + ((size_t)72 << 20));   // 16 MB  [B][N][H*D]

    cvt_x_kernel<<<(ROWS*DIM/8)/256, 256, 0, stream>>>(x, xb, ROWS*DIM/8);
    transpose_w_kernel<<<(NQKV/32)*(DIM/32), 256, 0, stream>>>(w_qkv, wqkvT, DIM, NQKV);
    transpose_w_kernel<<<(DIM/32)*(DIM/32), 256, 0, stream>>>(w_out, woutT, DIM, DIM);
    gemm1_kernel<<<(NQKV/128)*(ROWS/128), 256, 0, stream>>>(xb, wqkvT, q, k, v);
    attn_kernel<<<(BATCH*HEADS)*(SEQ/128), 256, 0, stream>>>(q, k, v, ao);
    gemm2_kernel<<<(DIM/128)*(ROWS/128), 256, 0, stream>>>(ao, woutT, b_out, out);
}